// Round 6
// baseline (181.572 us; speedup 1.0000x reference)
//
#include <hip/hip_runtime.h>
#include <hip/hip_bf16.h>

typedef __attribute__((ext_vector_type(8))) short  short8;
typedef __attribute__((ext_vector_type(4))) float  float4v;
typedef __attribute__((ext_vector_type(4))) unsigned short ushort4v;

#define NC    8192
#define TPIX  784      // 28*28
#define NB    8

// ws layout (bytes)
#define WS_M2    0                 // bf16 [784][160]   = 250880
#define WS_O     250880            // f32  [8192]       = 32768
#define WS_ZACC  283648            // f32  [8][784]     = 25088
#define WS_DACC  308736            // f32  [8][784]     = 25088
#define WS_ZPOS  333824            // f32  [8][25][25]  = 20000
#define WS_ZERO_OFF WS_ZACC
#define WS_ZERO_LEN 70176
#define WS_STUDB 360448            // bf16 [65536][160] = 20971520
#define WS_NEED  (360448 + 65536*320)

__device__ __forceinline__ unsigned short bf16rne(float f) {
    unsigned int u = __float_as_uint(f);
    u = (u + 0x7FFFu + ((u >> 16) & 1u)) >> 16;
    return (unsigned short)u;
}

__device__ __forceinline__ short8 cvt8(float4v a, float4v b) {
    union { __hip_bfloat162 h[4]; short8 s; } u;
    u.h[0] = __float22bfloat162_rn(float2{a[0], a[1]});
    u.h[1] = __float22bfloat162_rn(float2{a[2], a[3]});
    u.h[2] = __float22bfloat162_rn(float2{b[0], b[1]});
    u.h[3] = __float22bfloat162_rn(float2{b[2], b[3]});
    return u.s;
}

// ---------------- kernel 1: M2' = 10 * K[y,v] * K[x,u], bf16 [784][160] ----------------
__global__ void k_init_m2(unsigned short* __restrict__ m2) {
    int p  = blockIdx.x;           // 0..783
    int sp = threadIdx.x;          // 0..159
    int y = p / 28, x = p % 28;
    float val = 0.f;
    if (sp < 144) {
        int v = sp / 12, u = sp % 12;
        float kyv = 0.f, kxu = 0.f;
        for (int a = 0; a < 25; ++a) {
            float ctc = 0.9f + 1.05f * (float)a;
            int   i0  = (int)ctc; float wt = ctc - (float)i0;
            float Ay  = (i0 == y) ? (1.f - wt) : ((i0 + 1 == y) ? wt : 0.f);
            float Ax  = (i0 == x) ? (1.f - wt) : ((i0 + 1 == x) ? wt : 0.f);
            float csc = 0.7f + 0.4f * (float)a;
            int   j0  = (int)csc; float wsv = csc - (float)j0;
            float Bv  = (j0 == v) ? (1.f - wsv) : ((j0 + 1 == v) ? wsv : 0.f);
            float Bu  = (j0 == u) ? (1.f - wsv) : ((j0 + 1 == u) ? wsv : 0.f);
            kyv += Ay * Bv;
            kxu += Ax * Bu;
        }
        val = 10.f * kyv * kxu;
    }
    m2[p * 160 + sp] = bf16rne(val);
}

// ---------------- kernel 1b: pre-convert student -> padded bf16 [65536][160], o[c] -----
__launch_bounds__(256)
__global__ void k_pre(const float* __restrict__ student, const float* __restrict__ center,
                      unsigned short* __restrict__ studb, float* __restrict__ o) {
    const int tid = blockIdx.x * 256 + threadIdx.x;   // 0 .. 1310719
    const int row = tid / 20, ch = tid % 20;
    short8 hv = {0,0,0,0,0,0,0,0};
    if (ch < 18) {
        const float* src = student + (long long)row * 144 + ch * 8;
        hv = cvt8(*(const float4v*)(src), *(const float4v*)(src + 4));
    }
    *(short8*)(studb + (long long)row * 160 + ch * 8) = hv;
    if (ch == 0 && row < NC)
        o[row] = fmaf(36.0673762f, center[row], 233.7165966f);
}

// ---------------- kernel 2: request-slot-optimized fused GEMM + softmax reduce ---------
// Per-CU VMEM request slots are the scarce resource (~5cy/line). M2 A-frags come from
// LDS (0 slots), student B-frags 5 instr/16ch, teacher 6 instr/16ch x 96p = majority
// of slots carry teacher payload. Block: 512 thr (8 waves), 96-p chunk staged in LDS,
// 1024 channels in 8 k-iters (wave w: c = cw*1024 + k*128 + w*16 + l15).
// Lane (g,l15): D row p = pg*96 + t6*16 + 4g + i, col c = l15-channel.
__launch_bounds__(512, 4)
__global__ void k_main2(const float* __restrict__ teacher,
                        const unsigned short* __restrict__ m2,
                        const unsigned short* __restrict__ studb,
                        const float* __restrict__ o,
                        float* __restrict__ zacc, float* __restrict__ dacc) {
    __shared__ unsigned short m2s[96 * 168];   // 336 B rows (pad 16 B) ~2-way banks

    const int b  = blockIdx.z;
    const int cw = blockIdx.y;      // 0..7
    const int pg = blockIdx.x;      // 0..8
    const int t  = threadIdx.x;
    const int w = t >> 6, lane = t & 63, l15 = lane & 15, g = lane >> 4;

    // stage M2 chunk (rows pg*96 .. +95) into LDS; zeros beyond row 783
    for (int i = t; i < 3840; i += 512) {     // 96 rows x 40 ushort4-chunks
        const int r = i / 40, c4 = i % 40;
        const int rg = pg * 96 + r;
        ushort4v v = {0, 0, 0, 0};
        if (rg < TPIX) v = *(const ushort4v*)(m2 + rg * 160 + c4 * 4);
        *(ushort4v*)&m2s[r * 168 + c4 * 4] = v;
    }
    __syncthreads();    // LDS read-only hereafter; no further barriers

    float sE[24], sEY[24];
    #pragma unroll
    for (int j = 0; j < 24; ++j) { sE[j] = 0.f; sEY[j] = 0.f; }

    const long long tbase = (long long)(b * NC) * TPIX;

    for (int k = 0; k < 8; ++k) {
        const int c = cw * 1024 + k * 128 + w * 16 + l15;

        // student B-frags: 5 dwordx4 (16 ch x 64 B fully-used lines)
        const unsigned short* srow = studb + ((long long)(b * NC) + c) * 160;
        short8 bf[5];
        #pragma unroll
        for (int ks = 0; ks < 5; ++ks)
            bf[ks] = *(const short8*)(srow + ks * 32 + g * 8);
        const float oc = o[c];

        const float* trow = teacher + tbase + (long long)c * TPIX;

        #pragma unroll
        for (int t6 = 0; t6 < 6; ++t6) {
            if (pg * 6 + t6 > 48) continue;          // phantom tile: skip entirely
            const int p0 = pg * 96 + t6 * 16;

            // teacher: one float4/lane -> 16 ch x 64 B fully-used lines
            float4v tv = *(const float4v*)(trow + p0 + 4 * g);

            // M2 A-frags from LDS (zero VMEM slots)
            float4v acc = {0.f, 0.f, 0.f, 0.f};
            #pragma unroll
            for (int ks = 0; ks < 5; ++ks) {
                short8 af = *(const short8*)&m2s[(t6 * 16 + l15) * 168 + ks * 32 + g * 8];
                acc = __builtin_amdgcn_mfma_f32_16x16x32_bf16(af, bf[ks], acc, 0, 0, 0);
            }

            #pragma unroll
            for (int i = 0; i < 4; ++i) {
                float e = exp2f(fmaf(36.0673762f, tv[i], -oc));
                sE[t6 * 4 + i] += e;
                sEY[t6 * 4 + i] = fmaf(e, acc[i], sEY[t6 * 4 + i]);
            }
        }
    }

    // reduce over l15 (16 channels) and commit
    #pragma unroll
    for (int t6 = 0; t6 < 6; ++t6) {
        if (pg * 6 + t6 > 48) continue;
        #pragma unroll
        for (int i = 0; i < 4; ++i) {
            float e = sE[t6 * 4 + i], y = sEY[t6 * 4 + i];
            e += __shfl_xor(e, 1); e += __shfl_xor(e, 2); e += __shfl_xor(e, 4); e += __shfl_xor(e, 8);
            y += __shfl_xor(y, 1); y += __shfl_xor(y, 2); y += __shfl_xor(y, 4); y += __shfl_xor(y, 8);
            if (l15 == 0) {
                const int p = pg * 96 + t6 * 16 + 4 * g + i;
                atomicAdd(zacc + b * TPIX + p, e);
                atomicAdd(dacc + b * TPIX + p, y);
            }
        }
    }
}

// ---------------- fallback main (R5 structure, raw f32 student) ------------------------
__launch_bounds__(256, 2)
__global__ void k_main_fb(const float* __restrict__ teacher,
                          const float* __restrict__ student,
                          const float* __restrict__ center,
                          const unsigned short* __restrict__ m2,
                          float* __restrict__ zacc, float* __restrict__ dacc) {
    const int b  = blockIdx.z;
    const int cg = blockIdx.y;
    const int t  = threadIdx.x;
    const int w = t >> 6, lane = t & 63, l15 = lane & 15, g = lane >> 4;

    const int tile0 = (blockIdx.x * 4 + w) * 2;
    const bool va = (tile0     < 49);
    const bool vb = (tile0 + 1 < 49);
    const int p0a = va ? tile0 * 16 : 0;
    const int p0b = vb ? (tile0 + 1) * 16 : 0;

    short8 afa[5], afb[5];
    {
        const unsigned short* ra = m2 + (p0a + l15) * 160;
        const unsigned short* rb = m2 + (p0b + l15) * 160;
        #pragma unroll
        for (int ks = 0; ks < 5; ++ks) {
            afa[ks] = *(const short8*)(ra + ks * 32 + g * 8);
            afb[ks] = *(const short8*)(rb + ks * 32 + g * 8);
        }
    }

    float sEa[4] = {0.f,0.f,0.f,0.f}, sEYa[4] = {0.f,0.f,0.f,0.f};
    float sEb[4] = {0.f,0.f,0.f,0.f}, sEYb[4] = {0.f,0.f,0.f,0.f};
    const long long tbase = (long long)(b * NC) * TPIX;
    const long long sbase = (long long)(b * NC) * 144;
    const short8 zfrag = {0,0,0,0,0,0,0,0};

    for (int cc = 0; cc < 16; ++cc) {
        const int cA = cg * 256 + cc * 16 + l15;
        const float* sA = student + sbase + (long long)cA * 144;
        short8 bfA[5];
        #pragma unroll
        for (int ks = 0; ks < 4; ++ks)
            bfA[ks] = cvt8(*(const float4v*)(sA + ks * 32 + g * 8),
                           *(const float4v*)(sA + ks * 32 + g * 8 + 4));
        bfA[4] = (g < 2) ? cvt8(*(const float4v*)(sA + 128 + g * 8),
                                *(const float4v*)(sA + 128 + g * 8 + 4)) : zfrag;
        const float oA = fmaf(36.0673762f, center[cA], 233.7165966f);
        const float* trA = teacher + tbase + (long long)cA * TPIX;
        float4v tva = *(const float4v*)(trA + p0a + 4 * g);
        float4v tvb = *(const float4v*)(trA + p0b + 4 * g);
        float4v acca = {0.f,0.f,0.f,0.f}, accb = {0.f,0.f,0.f,0.f};
        #pragma unroll
        for (int ks = 0; ks < 5; ++ks) {
            acca = __builtin_amdgcn_mfma_f32_16x16x32_bf16(afa[ks], bfA[ks], acca, 0, 0, 0);
            accb = __builtin_amdgcn_mfma_f32_16x16x32_bf16(afb[ks], bfA[ks], accb, 0, 0, 0);
        }
        #pragma unroll
        for (int i = 0; i < 4; ++i) {
            float e0 = exp2f(fmaf(36.0673762f, tva[i], -oA));
            sEa[i] += e0;  sEYa[i] = fmaf(e0, acca[i], sEYa[i]);
            float e1 = exp2f(fmaf(36.0673762f, tvb[i], -oA));
            sEb[i] += e1;  sEYb[i] = fmaf(e1, accb[i], sEYb[i]);
        }
    }

    #pragma unroll
    for (int i = 0; i < 4; ++i) {
        float e0 = sEa[i], y0 = sEYa[i], e1 = sEb[i], y1 = sEYb[i];
        e0 += __shfl_xor(e0, 1); e0 += __shfl_xor(e0, 2); e0 += __shfl_xor(e0, 4); e0 += __shfl_xor(e0, 8);
        y0 += __shfl_xor(y0, 1); y0 += __shfl_xor(y0, 2); y0 += __shfl_xor(y0, 4); y0 += __shfl_xor(y0, 8);
        e1 += __shfl_xor(e1, 1); e1 += __shfl_xor(e1, 2); e1 += __shfl_xor(e1, 4); e1 += __shfl_xor(e1, 8);
        y1 += __shfl_xor(y1, 1); y1 += __shfl_xor(y1, 2); y1 += __shfl_xor(y1, 4); y1 += __shfl_xor(y1, 8);
        if (l15 == 0) {
            if (va) {
                atomicAdd(zacc + b * TPIX + p0a + 4 * g + i, e0);
                atomicAdd(dacc + b * TPIX + p0a + 4 * g + i, y0);
            }
            if (vb) {
                atomicAdd(zacc + b * TPIX + p0b + 4 * g + i, e1);
                atomicAdd(dacc + b * TPIX + p0b + 4 * g + i, y1);
            }
        }
    }
}

// ---------------- kernel 3: per-position LSE partials (register-only, no LDS) ----------
__launch_bounds__(256)
__global__ void k_lse(const float* __restrict__ student, float* __restrict__ zpos) {
    const int cg = blockIdx.x;   // 0..3
    const int a  = blockIdx.y;
    const int b  = blockIdx.z;
    const int t  = threadIdx.x;

    const float cv = 0.7f + 0.4f * (float)a;
    const int   v0 = (int)cv;
    const float wv = cv - (float)v0;
    const float W0 = 10.f * (1.f - wv), W1 = 10.f * wv;

    float accs[25];
    #pragma unroll
    for (int p = 0; p < 25; ++p) accs[p] = 0.f;

    for (int j = 0; j < 8; ++j) {
        const int c = cg * 2048 + 256 * j + t;
        const float* row = student + (long long)(b * NC + c) * 144 + v0 * 12;
        float4v r0 = *(const float4v*)(row + 0);
        float4v r1 = *(const float4v*)(row + 4);
        float4v r2 = *(const float4v*)(row + 8);
        float4v s0 = *(const float4v*)(row + 12);
        float4v s1 = *(const float4v*)(row + 16);
        float4v s2 = *(const float4v*)(row + 20);

        float R[12];
        #pragma unroll
        for (int u = 0; u < 4; ++u) {
            R[u]     = fmaf(W0, r0[u], W1 * s0[u]);
            R[u + 4] = fmaf(W0, r1[u], W1 * s1[u]);
            R[u + 8] = fmaf(W0, r2[u], W1 * s2[u]);
        }
        #pragma unroll
        for (int p = 0; p < 25; ++p) {
            const float cu = 0.7f + 0.4f * (float)p;
            const int   u0 = (int)cu;
            const float wu = cu - (float)u0;
            float sc = fmaf(1.f - wu, R[u0], wu * R[u0 + 1]);       // = 10*s_common
            accs[p] += exp2f(fmaf(1.44269504f, sc, -86.5617025f));  // exp(sc - 60)
        }
    }

    #pragma unroll
    for (int p = 0; p < 25; ++p) {
        float v = accs[p];
        #pragma unroll
        for (int m = 1; m < 64; m <<= 1) v += __shfl_xor(v, m);
        accs[p] = v;
    }
    if ((t & 63) == 0) {
        #pragma unroll
        for (int p = 0; p < 25; ++p)
            atomicAdd(zpos + (b * 25 + a) * 25 + p, accs[p]);
    }
}

// ---------------- kernel 4: final combine ----------------
__global__ void k_final(const float* __restrict__ zacc, const float* __restrict__ dacc,
                        const float* __restrict__ zpos, float* __restrict__ out) {
    __shared__ float red[8];
    int t = threadIdx.x;   // 256
    float s = 0.f;
    for (int i = t; i < 5000; i += 256) s += 60.f + logf(zpos[i]);
    for (int i = t; i < NB * TPIX; i += 256) s -= dacc[i] / zacc[i];
    for (int m = 1; m < 64; m <<= 1) s += __shfl_xor(s, m);
    if ((t & 63) == 0) red[t >> 6] = s;
    __syncthreads();
    if (t == 0) out[0] = (red[0] + red[1] + red[2] + red[3]) * (1.f / 5000.f);
}

extern "C" void kernel_launch(void* const* d_in, const int* in_sizes, int n_in,
                              void* d_out, int out_size, void* d_ws, size_t ws_size,
                              hipStream_t stream) {
    const float* teacher = (const float*)d_in[0];
    const float* student = (const float*)d_in[1];
    const float* center  = (const float*)d_in[2];

    char* ws = (char*)d_ws;
    unsigned short* m2    = (unsigned short*)(ws + WS_M2);
    float*          oarr  = (float*)(ws + WS_O);
    float*          zacc  = (float*)(ws + WS_ZACC);
    float*          dacc  = (float*)(ws + WS_DACC);
    float*          zpos  = (float*)(ws + WS_ZPOS);
    unsigned short* studb = (unsigned short*)(ws + WS_STUDB);

    hipMemsetAsync(ws + WS_ZERO_OFF, 0, WS_ZERO_LEN, stream);
    k_init_m2<<<784, 160, 0, stream>>>(m2);

    if (ws_size >= (size_t)WS_NEED) {
        k_pre<<<5120, 256, 0, stream>>>(student, center, studb, oarr);
        k_main2<<<dim3(9, 8, 8), 512, 0, stream>>>(teacher, m2, studb, oarr, zacc, dacc);
    } else {
        k_main_fb<<<dim3(7, 32, 8), 256, 0, stream>>>(teacher, student, center, m2, zacc, dacc);
    }
    k_lse<<<dim3(4, 25, 8), 256, 0, stream>>>(student, zpos);
    k_final<<<1, 256, 0, stream>>>(zacc, dacc, zpos, (float*)d_out);
}